// Round 1
// baseline (163.681 us; speedup 1.0000x reference)
//
#include <hip/hip_runtime.h>
#include <math.h>

#define Bsz 8
#define Udim 13
#define Vdim 13
#define Hdim 128
#define Wdim 160
#define HW (Hdim * Wdim)          // 20480
#define UV (Udim * Vdim)          // 169
#define TRUNC 4
#define NPIX (Bsz * HW)           // 163840 = 2560 * 64
#define NG 4                      // plane-groups: one per wave of the block
#define PPG 43                    // ceil(169/4) planes per thread
#define PIXB 64                   // pixels per block (= one wave width)

// Cooperative design: each block owns 64 pixels; the block's 4 waves each
// hold a 43-plane slice of the 169 (u,v) planes in registers (~70 VGPR vs
// ~200 for the monolithic version). Argmax and masked-softmax partial sums
// are exchanged through 6 KB of LDS. HBM traffic is unchanged (single
// pass, fully coalesced 256B/wave loads); occupancy and grid granularity
// rise ~3x (2560 blocks, ~24 waves/CU vs 8).
__global__ __launch_bounds__(256, 4) void flow_regression_kernel(
    const float* __restrict__ x, float* __restrict__ out) {
    const int lane = threadIdx.x & 63;
    const int g    = threadIdx.x >> 6;          // wave-uniform group 0..3
    const int p    = blockIdx.x * PIXB + lane;  // pixel this lane owns
    const int b    = p / HW;
    const int hw   = p - b * HW;
    const int lo   = g * PPG;                   // first absolute plane idx

    const float* base = x + (size_t)b * UV * HW + (size_t)lo * HW + hw;

    // ---- Load this wave's plane slice (coalesced, independent) ----
    float vals[PPG];
    #pragma unroll
    for (int j = 0; j < PPG; ++j) {
        // wave-uniform predicate: only group 3's last 3 slots are dead
        vals[j] = (lo + j < UV) ? base[(size_t)j * HW] : -INFINITY;
    }

    // ---- Local argmax over the slice (strict > => lowest index on ties) ----
    float m  = vals[0];
    int   mi = lo;
    #pragma unroll
    for (int j = 1; j < PPG; ++j) {
        if (vals[j] > m) { m = vals[j]; mi = lo + j; }
    }

    __shared__ float sM[NG][PIXB];
    __shared__ int   sI[NG][PIXB];
    __shared__ float sS[NG][PIXB], sU[NG][PIXB], sV[NG][PIXB];

    sM[g][lane] = m;
    sI[g][lane] = mi;
    __syncthreads();

    // ---- Global argmax: scan groups in order => first-index tie-break ----
    float gm  = sM[0][lane];
    int   gmi = sI[0][lane];
    #pragma unroll
    for (int q = 1; q < NG; ++q) {
        float mq = sM[q][lane];
        int   iq = sI[q][lane];
        if (mq > gm) { gm = mq; gmi = iq; }
    }
    const int ui = gmi / Vdim;
    const int vi = gmi - ui * Vdim;

    // ---- Masked softmax partial sums over this wave's slice ----
    float sum = 0.f, wu = 0.f, wv = 0.f;
    int u = lo / Vdim;
    int v = lo - u * Vdim;
    #pragma unroll
    for (int j = 0; j < PPG; ++j) {
        bool in = (u - ui <= TRUNC) && (ui - u <= TRUNC) &&
                  (v - vi <= TRUNC) && (vi - v <= TRUNC);
        // tail slots hold -INF -> e == 0 exactly, so no i<UV check needed
        float e = in ? __expf(vals[j] - gm) : 0.f;
        sum += e;
        wu  += e * (float)(u - 6);
        wv  += e * (float)(v - 6);
        if (++v == Vdim) { v = 0; ++u; }
    }

    sS[g][lane] = sum;
    sU[g][lane] = wu;
    sV[g][lane] = wv;
    __syncthreads();

    // ---- Wave 0 reduces the 4 partials and writes the two flow planes ----
    if (g == 0) {
        float S = sS[0][lane] + sS[1][lane] + sS[2][lane] + sS[3][lane];
        float U = sU[0][lane] + sU[1][lane] + sU[2][lane] + sU[3][lane];
        float V = sV[0][lane] + sV[1][lane] + sV[2][lane] + sV[3][lane];
        float inv = 1.0f / S;
        float* ob = out + (size_t)b * 2 * HW + hw;
        ob[0]  = U * inv;   // flowU plane
        ob[HW] = V * inv;   // flowV plane
    }
}

extern "C" void kernel_launch(void* const* d_in, const int* in_sizes, int n_in,
                              void* d_out, int out_size, void* d_ws, size_t ws_size,
                              hipStream_t stream) {
    const float* x = (const float*)d_in[0];
    float* out = (float*)d_out;
    flow_regression_kernel<<<NPIX / PIXB, 256, 0, stream>>>(x, out);
}